// Round 3
// baseline (131.679 us; speedup 1.0000x reference)
//
#include <hip/hip_runtime.h>

// Problem constants (fixed by the reference).
#define N_NODES 10000
#define DEG     32
#define CH      16
#define IN_DIM  4
#define BATCH   8
#define E_EDGES (N_NODES * DEG)        // 320000
#define WI_STRIDE (E_EDGES * CH)       // 5,120,000 floats between w[i] planes
#define P_COUNT 625                    // 512*625 == E_EDGES : gather period in n
#define LX_STRIDE 36                   // 32 floats/row + 4 pad (16B-aligned)

// Kernel 1: transpose/pad x[B][N][4] -> xt[N+1][B][4] (node-major, 128 B/node).
// r1 ablation: direct 16 B-granule gathers from x cost ~6 us more than this
// kernel + 128 B-row gathers (4x fewer L2 lines per Stage-A wave).
__global__ __launch_bounds__(256) void lcg_transpose(const float* __restrict__ x,
                                                     float* __restrict__ xt) {
    int t = blockIdx.x * 256 + threadIdx.x;
    if (t < BATCH * N_NODES) {
        int b = t / N_NODES;
        int node = t - b * N_NODES;
        float4 v = *(const float4*)(x + 4 * t);          // x[b][node][0..3]
        *(float4*)(xt + node * 32 + b * 4) = v;
    } else if (t < BATCH * N_NODES + 8) {
        int r = t - BATCH * N_NODES;                     // zero pad row N_NODES
        *(float4*)(xt + N_NODES * 32 + r * 4) = make_float4(0.f, 0.f, 0.f, 0.f);
    }
}

// Kernel 2: one block per p (0..624), 512 threads = 8 waves.
// All 16 n's with n mod 625 == p share the same 512 gathered rows
// (k = 512p + 16d + c). r2 budget: 16 waves x 64 KB LDS reads = 1 MB/block
// (625 MB total, ~12.5 us of LDS pipe) tied with the 13 us HBM weight
// stream as co-limiter. Change: each wave now owns TWO n's
// (n0 = p+625j, n1 = p+625(j+8)), reading each LDS row once and applying
// both weight sets -> LDS reads halve to 312 MB (~6 us), FMAs/weight
// traffic unchanged, per-n summation order bitwise identical.
// Occupancy: 73.7 KB LDS -> 2 blocks/CU = 16 waves/CU; weight latency
// covered by 8 in-flight nt loads/wave (depth-2 pipeline kept from r2).
__global__ __launch_bounds__(512, 4) void lcg_main(
    const float* __restrict__ xt,     // [N+1][32]
    const int*   __restrict__ edges,  // [E]
    const float* __restrict__ w,      // [4][E][16]
    float*       __restrict__ out)    // [8][N][16]
{
    __shared__ float lx[512 * LX_STRIDE];   // 73728 B

    int p = blockIdx.x;
    int t = threadIdx.x;              // 0..511

    int lane = t & 63;
    int j    = t >> 6;                // wave id 0..7
    int c    = lane & 15;
    int dq   = lane >> 4;             // 0..3
    int n0   = p + P_COUNT * j;
    int n1   = p + P_COUNT * (j + 8);

    // weight base: w[i][32n + (4ds+dq)][c] = w + i*WI_STRIDE + n*512 + 64*ds + lane
    const float* wa = w + n0 * (DEG * CH) + lane;
    const float* wbp = w + n1 * (DEG * CH) + lane;

    // ds=0 prefetch: flies under the Stage-A gather (drained by the same
    // vmcnt(0) the compiler emits before the barrier).
    float u0 = __builtin_nontemporal_load(wa);
    float u1 = __builtin_nontemporal_load(wa + WI_STRIDE);
    float u2 = __builtin_nontemporal_load(wa + 2 * WI_STRIDE);
    float u3 = __builtin_nontemporal_load(wa + 3 * WI_STRIDE);
    float v0 = __builtin_nontemporal_load(wbp);
    float v1 = __builtin_nontemporal_load(wbp + WI_STRIDE);
    float v2 = __builtin_nontemporal_load(wbp + 2 * WI_STRIDE);
    float v3 = __builtin_nontemporal_load(wbp + 3 * WI_STRIDE);

    // ---- Stage A: edges + gather into LDS (rows s = 0..511) ----
    // 512 threads: sub = t&7 picks the 16 B chunk, rg = t>>3 (0..63),
    // rows s = rg + 64k, k<8. Each 8-lane group loads one contiguous
    // 128 B node row (same coalescing as the 1024-thread version).
    {
        int sub = t & 7;
        int rg  = t >> 3;
        const int* ep = edges + 512 * p;
        int nd[8];
#pragma unroll
        for (int k = 0; k < 8; k++) nd[k] = ep[rg + 64 * k];
#pragma unroll
        for (int k = 0; k < 8; k++) {
            int s = rg + 64 * k;
            float4 vv = *(const float4*)(xt + nd[k] * 32 + sub * 4);
            *(float4*)(&lx[s * LX_STRIDE + sub * 4]) = vv;
        }
    }
    __syncthreads();

    // ---- Stage B ----
    float acc0[BATCH], acc1[BATCH];
#pragma unroll
    for (int b = 0; b < BATCH; b++) { acc0[b] = 0.0f; acc1[b] = 0.0f; }

    // LDS row for (d = 4ds+dq, c): s = 16d + c -> base (16dq + c)*36, step 64*36
    const float* lrow = &lx[(16 * dq + c) * LX_STRIDE];

#pragma unroll 1
    for (int ds = 0; ds < 8; ds++) {
        // Prefetch next iteration's weights (ds=7 harmlessly re-reads ds=0).
        int nxt = 64 * ((ds + 1) & 7);
        float nu0 = __builtin_nontemporal_load(wa + nxt);
        float nu1 = __builtin_nontemporal_load(wa + nxt + WI_STRIDE);
        float nu2 = __builtin_nontemporal_load(wa + nxt + 2 * WI_STRIDE);
        float nu3 = __builtin_nontemporal_load(wa + nxt + 3 * WI_STRIDE);
        float nv0 = __builtin_nontemporal_load(wbp + nxt);
        float nv1 = __builtin_nontemporal_load(wbp + nxt + WI_STRIDE);
        float nv2 = __builtin_nontemporal_load(wbp + nxt + 2 * WI_STRIDE);
        float nv3 = __builtin_nontemporal_load(wbp + nxt + 3 * WI_STRIDE);

        const float* lr = lrow + ds * (64 * LX_STRIDE);
#pragma unroll
        for (int b = 0; b < BATCH; b++) {
            float4 xq = *(const float4*)(lr + 4 * b);
            acc0[b] += xq.x * u0 + xq.y * u1 + xq.z * u2 + xq.w * u3;
            acc1[b] += xq.x * v0 + xq.y * v1 + xq.z * v2 + xq.w * v3;
        }
        u0 = nu0; u1 = nu1; u2 = nu2; u3 = nu3;
        v0 = nv0; v1 = nv1; v2 = nv2; v3 = nv3;
    }

    // reduce over dq groups (lanes l, l^16, l^32, l^48)
#pragma unroll
    for (int b = 0; b < BATCH; b++) {
        acc0[b] += __shfl_xor(acc0[b], 16, 64);
        acc0[b] += __shfl_xor(acc0[b], 32, 64);
        acc1[b] += __shfl_xor(acc1[b], 16, 64);
        acc1[b] += __shfl_xor(acc1[b], 32, 64);
    }

    // dq group g stores batches 2g, 2g+1 (16 c-lanes -> one 64 B line per b,n)
    int ob0 = n0 * CH + c;
    int ob1 = n1 * CH + c;
    __builtin_nontemporal_store(acc0[2 * dq + 0],
        out + (2 * dq + 0) * (N_NODES * CH) + ob0);
    __builtin_nontemporal_store(acc0[2 * dq + 1],
        out + (2 * dq + 1) * (N_NODES * CH) + ob0);
    __builtin_nontemporal_store(acc1[2 * dq + 0],
        out + (2 * dq + 0) * (N_NODES * CH) + ob1);
    __builtin_nontemporal_store(acc1[2 * dq + 1],
        out + (2 * dq + 1) * (N_NODES * CH) + ob1);
}

extern "C" void kernel_launch(void* const* d_in, const int* in_sizes, int n_in,
                              void* d_out, int out_size, void* d_ws, size_t ws_size,
                              hipStream_t stream) {
    const float* x     = (const float*)d_in[0];   // [8][10000][4] f32
    const int*   edges = (const int*)d_in[1];     // [320000] int32 (jax x64 off)
    const float* w     = (const float*)d_in[2];   // [4][320000][16] f32
    float* out = (float*)d_out;                   // [8][10000][16] f32
    float* xt  = (float*)d_ws;                    // (10001*32) floats = 1.28 MB

    int tr_total  = BATCH * N_NODES + 8;                  // 80008
    int tr_blocks = (tr_total + 255) / 256;               // 313
    lcg_transpose<<<tr_blocks, 256, 0, stream>>>(x, xt);

    lcg_main<<<P_COUNT, 512, 0, stream>>>(xt, edges, w, out);
}